// Round 15
// baseline (312.462 us; speedup 1.0000x reference)
//
#include <hip/hip_runtime.h>
#include <hip/hip_bf16.h>
#include <math.h>

#define F_IN 128
#define F_HID 64
#define F_OUT 40
#define BN_EPS 1e-5f

typedef __attribute__((ext_vector_type(8))) short short8;
typedef __attribute__((ext_vector_type(4))) float f32x4;

__device__ __forceinline__ float bflo(unsigned u) { return __uint_as_float(u << 16); }
__device__ __forceinline__ float bfhi(unsigned u) { return __uint_as_float(u & 0xffff0000u); }
__device__ __forceinline__ unsigned pack2(float a, float b) {
    __hip_bfloat162 p;
    p.x = __float2bfloat16(a);
    p.y = __float2bfloat16(b);
    return *(unsigned*)&p;
}

// ============ CSR build via 2-level LDS counting sort.
// r1: global atomics write through memory-side at 32B/op -> never on hot path.
// r4/r10: node reordering destroys locality -> natural node order everywhere.
// r6: edge-parallel LDS f32 atomics serialize on the LDS atomic pipe.
// r7/r8: per-XCD gather region must be < ~3.5MB; rows wide/aligned.
// r11: grid.sync costs ~60us each on 8 XCDs -> cooperative fusion dead.
// r12-r14: conv1 pinned at ~46us across 6 structural variants (mixed
//     VALU-issue + L2 random-service floor; not MLP, not VGPR, not requests).
// r15: build write-amp fix: nblk 512->128 -> per-(bucket,block) runs grow
//     8->32 edges (32B->128B, full lines); bh table 4x smaller (L2-fit).

// ---- pass 1: per-(bucket, block) coarse histogram; block 0 zeroes cursor ----
__global__ __launch_bounds__(256) void k_hist(const int* __restrict__ col, int E,
                                              int chunk, int nblk, int NB,
                                              int* __restrict__ bh,
                                              int* __restrict__ cursor) {
    __shared__ int hist[512];
    int t = threadIdx.x, blk = blockIdx.x;
    if (blk == 0 && t < 4) cursor[t] = 0;   // k_alloc runs in a later dispatch
    for (int i = t; i < NB; i += 256) hist[i] = 0;
    __syncthreads();
    int e0 = blk * chunk, e1 = min(E, e0 + chunk);
    for (int e = e0 + t; e < e1; e += 256)
        atomicAdd(&hist[col[e] >> 8], 1);
    __syncthreads();
    for (int i = t; i < NB; i += 256)
        bh[(size_t)i * nblk + blk] = hist[i];
}

// ---- pass 2: per-bucket scan of its nblk cells; 1 cursor atomic per bucket. ----
__global__ __launch_bounds__(256) void k_alloc(int* __restrict__ bh,
                                               int* __restrict__ bb,
                                               int* __restrict__ bt,
                                               int* __restrict__ cursor, int nblk) {
    int t = threadIdx.x, bu = blockIdx.x;
    int lane = t & 63, wv = t >> 6;
    size_t base_i = (size_t)bu * nblk;
    int i0 = 2 * t, i1 = 2 * t + 1;
    int a = (i0 < nblk) ? bh[base_i + i0] : 0;
    int b = (i1 < nblk) ? bh[base_i + i1] : 0;
    int p = a + b;
    int scan = p;
    #pragma unroll
    for (int o = 1; o < 64; o <<= 1) {
        int tt = __shfl_up(scan, o);
        if (lane >= o) scan += tt;
    }
    __shared__ int wsum[4];
    if (lane == 63) wsum[wv] = scan;
    __syncthreads();
    if (t == 0) {
        int s0 = wsum[0], s1 = wsum[1], s2 = wsum[2], s3 = wsum[3];
        int total = s0 + s1 + s2 + s3;
        int base = atomicAdd(cursor, total);
        bb[bu] = base;
        bt[bu] = total;
        wsum[0] = base; wsum[1] = base + s0;
        wsum[2] = base + s0 + s1; wsum[3] = base + s0 + s1 + s2;
    }
    __syncthreads();
    int excl = wsum[wv] + scan - p;   // absolute start of cell i0
    if (i0 < nblk) bh[base_i + i0] = excl;
    if (i1 < nblk) bh[base_i + i1] = excl + a;
}

// ---- pass 3: scatter edges into bucket-partitioned order via LDS cursors. ----
__global__ __launch_bounds__(256) void k_scatter(const int* __restrict__ row,
                                                 const int* __restrict__ col,
                                                 int E, int chunk, int nblk, int NB,
                                                 const int* __restrict__ bh,
                                                 unsigned* __restrict__ bpk) {
    __shared__ int cur[512];
    int t = threadIdx.x, blk = blockIdx.x;
    for (int i = t; i < NB; i += 256) cur[i] = bh[(size_t)i * nblk + blk];
    __syncthreads();
    int e0 = blk * chunk, e1 = min(E, e0 + chunk);
    for (int e = e0 + t; e < e1; e += 256) {
        int c = col[e];
        int pos = atomicAdd(&cur[c >> 8], 1);
        bpk[pos] = ((unsigned)row[e] << 8) | (unsigned)(c & 255);
    }
}

// ---- pass 4: per-bucket fine histogram + scan -> off/endp/dinv; place srcs. ----
__global__ __launch_bounds__(256) void k_fine(const unsigned* __restrict__ bpk,
                                              const int* __restrict__ bb,
                                              const int* __restrict__ bt,
                                              int* __restrict__ off,
                                              int* __restrict__ endp,
                                              float* __restrict__ dinv,
                                              int* __restrict__ srcs, int n) {
    __shared__ int fine[256];
    __shared__ int wsum[4];
    int t = threadIdx.x, bu = blockIdx.x;
    int lane = t & 63, wv = t >> 6;
    fine[t] = 0;
    __syncthreads();
    int base = bb[bu], tot = bt[bu];
    for (int i = t; i < tot; i += 256)
        atomicAdd(&fine[bpk[base + i] & 255], 1);
    __syncthreads();
    int d = fine[t];
    int scan = d;
    #pragma unroll
    for (int o = 1; o < 64; o <<= 1) {
        int tt = __shfl_up(scan, o);
        if (lane >= o) scan += tt;
    }
    if (lane == 63) wsum[wv] = scan;
    __syncthreads();
    if (t == 0) {
        int s0 = wsum[0], s1 = wsum[1], s2 = wsum[2];
        wsum[0] = 0;
        wsum[1] = s0;
        wsum[2] = s0 + s1;
        wsum[3] = s0 + s1 + s2;
    }
    __syncthreads();
    int o_node = base + wsum[wv] + scan - d;   // absolute segment start
    int node = bu * 256 + t;
    if (node < n) {
        off[node] = o_node;
        endp[node] = o_node + d;
        dinv[node] = rsqrtf((float)d + 1.0f);  // +1 self-loop
    }
    __syncthreads();
    fine[t] = o_node;                          // reuse as cursors
    __syncthreads();
    for (int i = t; i < tot; i += 256) {
        unsigned v = bpk[base + i];
        int pos = atomicAdd(&fine[v & 255], 1);
        srcs[pos] = (int)(v >> 8);
    }
}

// ---- h1' = dinv * (BN(x) @ W1) via MFMA bf16. Block 0 also zeroes the
//      h1u/h2u pad rows (row n) consumed by idle gather lanes. ----
__global__ __launch_bounds__(256) void k_gemm1(
        const float* __restrict__ x, const float* __restrict__ gamma,
        const float* __restrict__ beta, const float* __restrict__ mean,
        const float* __restrict__ var, const float* __restrict__ W1,
        const float* __restrict__ dinv, unsigned* __restrict__ h1u,
        unsigned* __restrict__ h2u, int n) {
    __shared__ unsigned short xt[64 * 136];     // 64 rows x 272B (pad 8 bf16)
    __shared__ float bs[F_IN], bt[F_IN];
    int t = threadIdx.x;
    if (blockIdx.x == 0) {
        size_t R1 = ((size_t)n + 1) * 8;
        size_t R2 = ((size_t)n + 1) * 10;
        if (t < 32) h1u[(size_t)(t >> 3) * R1 + (size_t)n * 8 + (t & 7)] = 0u;
        if (t >= 32 && t < 52) {
            int q = t - 32;
            h2u[(size_t)(q / 10) * R2 + (size_t)n * 10 + (q % 10)] = 0u;
        }
    }
    if (t < F_IN) {
        float s = rsqrtf(var[t] + BN_EPS) * gamma[t];
        bs[t] = s;
        bt[t] = beta[t] - mean[t] * s;
    }
    int lane = t & 63, wv = t >> 6;
    int quad = lane >> 4, c = lane & 15;
    short8 Bf[4][4];
    #pragma unroll
    for (int nt = 0; nt < 4; ++nt)
        #pragma unroll
        for (int ks = 0; ks < 4; ++ks) {
            short8 v;
            #pragma unroll
            for (int j = 0; j < 8; ++j) {
                int k = ks * 32 + quad * 8 + j;
                __hip_bfloat16 hb = __float2bfloat16(W1[k * F_HID + nt * 16 + c]);
                v[j] = *(short*)&hb;
            }
            Bf[nt][ks] = v;
        }
    __syncthreads();                            // bs/bt ready
    int nb = blockIdx.x * 64;
    #pragma unroll
    for (int it = 0; it < 8; ++it) {
        int i = t + 256 * it;                   // float4 slot: 2048 total
        int node = i >> 5, k4 = i & 31;
        int gn = nb + node;
        float4 v = make_float4(0.f, 0.f, 0.f, 0.f);
        if (gn < n) v = *(const float4*)(x + (size_t)gn * F_IN + k4 * 4);
        float4 sv = *(const float4*)(bs + k4 * 4);
        float4 tv = *(const float4*)(bt + k4 * 4);
        unsigned u0 = pack2(v.x * sv.x + tv.x, v.y * sv.y + tv.y);
        unsigned u1 = pack2(v.z * sv.z + tv.z, v.w * sv.w + tv.w);
        *(uint2*)(xt + node * 136 + k4 * 4) = make_uint2(u0, u1);
    }
    __syncthreads();
    const unsigned short* arow = xt + (wv * 16 + c) * 136;
    f32x4 acc[4] = {f32x4{0.f,0.f,0.f,0.f}, f32x4{0.f,0.f,0.f,0.f},
                    f32x4{0.f,0.f,0.f,0.f}, f32x4{0.f,0.f,0.f,0.f}};
    #pragma unroll
    for (int ks = 0; ks < 4; ++ks) {
        short8 af = *(const short8*)(arow + ks * 32 + quad * 8);  // ds_read_b128
        #pragma unroll
        for (int nt = 0; nt < 4; ++nt)
            acc[nt] = __builtin_amdgcn_mfma_f32_16x16x32_bf16(af, Bf[nt][ks],
                                                              acc[nt], 0, 0, 0);
    }
    size_t R1 = ((size_t)n + 1) * 8;
    #pragma unroll
    for (int r = 0; r < 4; ++r) {
        int node = nb + wv * 16 + quad * 4 + r;
        if (node < n) {
            float d = dinv[node];
            #pragma unroll
            for (int nt = 0; nt < 4; ++nt) {
                __hip_bfloat16 hb = __float2bfloat16(acc[nt][r] * d);
                unsigned short* dst =
                    (unsigned short*)(h1u + (size_t)nt * R1 + (size_t)node * 8) + c;
                *dst = *(unsigned short*)&hb;
            }
        }
    }
}

// ---- conv1: natural-order gather, slice pinned to XCD pair (3.2MB region,
//      L2-resident). 8 lanes/node, 4-batch unroll. ~46us floor (r12-r14). ----
__global__ __launch_bounds__(256, 8) void k_conv1(
        const unsigned* __restrict__ h1u, const int* __restrict__ srcs,
        const int* __restrict__ off, const int* __restrict__ endp,
        const float* __restrict__ dinv, const float* __restrict__ b1,
        unsigned* __restrict__ hus, int n, int nb1) {
    int bid = blockIdx.x;
    int slice = (bid & 7) >> 1;
    int idx = ((bid >> 3) << 1) | (bid & 1);
    if (idx >= nb1) return;
    int lane = threadIdx.x & 63;
    int g = lane >> 3, f = lane & 7, gb = g * 8;
    const unsigned* base = h1u + (size_t)slice * (((size_t)n + 1) * 8);
    int node = idx * 32 + (threadIdx.x >> 6) * 8 + g;
    int nodec = (node < n) ? node : n;
    int j = (node < n) ? off[node] : 0;
    int e = (node < n) ? endp[node] : 0;
    float a0 = 0.f, a1 = 0.f;
    while (__any(j < e)) {
        int sv0 = (j +      f < e) ? srcs[j + f]      : n;
        int sv1 = (j + 8  + f < e) ? srcs[j + 8 + f]  : n;
        int sv2 = (j + 16 + f < e) ? srcs[j + 16 + f] : n;
        int sv3 = (j + 24 + f < e) ? srcs[j + 24 + f] : n;
        #pragma unroll
        for (int k = 0; k < 8; ++k) {
            int s = __shfl(sv0, gb + k);
            unsigned u = base[(size_t)s * 8 + f];
            a0 += bflo(u); a1 += bfhi(u);
        }
        #pragma unroll
        for (int k = 0; k < 8; ++k) {
            int s = __shfl(sv1, gb + k);
            unsigned u = base[(size_t)s * 8 + f];
            a0 += bflo(u); a1 += bfhi(u);
        }
        #pragma unroll
        for (int k = 0; k < 8; ++k) {
            int s = __shfl(sv2, gb + k);
            unsigned u = base[(size_t)s * 8 + f];
            a0 += bflo(u); a1 += bfhi(u);
        }
        #pragma unroll
        for (int k = 0; k < 8; ++k) {
            int s = __shfl(sv3, gb + k);
            unsigned u = base[(size_t)s * 8 + f];
            a0 += bflo(u); a1 += bfhi(u);
        }
        j += 32;
    }
    unsigned us = base[(size_t)nodec * 8 + f];
    float d = (node < n) ? dinv[node] : 0.f;
    float2 bb = ((const float2*)b1)[slice * 8 + f];
    float h0 = fmaxf(d * (a0 + bflo(us)) + bb.x, 0.f);
    float h1 = fmaxf(d * (a1 + bfhi(us)) + bb.y, 0.f);
    if (node < n)
        hus[(size_t)slice * ((size_t)n * 8) + (size_t)node * 8 + f] = pack2(h0, h1);
}

// ---- h2' = dinv * (h @ W2); output 2 regions x (n+1)*10 dwords ----
__global__ __launch_bounds__(64) void k_gemm2(
        const unsigned* __restrict__ hus, const float* __restrict__ W2,
        const float* __restrict__ dinv, unsigned* __restrict__ h2u, int n) {
    __shared__ float xl[64 * 66];
    int lane = threadIdx.x;
    int nb = blockIdx.x * 64;
    int tn = lane >> 5;
    int q = lane & 31;
    size_t hN = (size_t)n * 8;
    for (int it = 0; it < 32; ++it) {
        int r = it * 2 + tn;
        int node = nb + r;
        unsigned u = 0;
        if (node < n) u = hus[(size_t)(q >> 3) * hN + (long)node * 8 + (q & 7)];
        xl[r * 66 + 2 * q]     = bflo(u);
        xl[r * 66 + 2 * q + 1] = bfhi(u);
    }
    __syncthreads();
    float acc[F_OUT];
    #pragma unroll
    for (int f = 0; f < F_OUT; ++f) acc[f] = 0.f;
    for (int k = 0; k < F_HID; ++k) {
        float xv = xl[lane * 66 + k];
        const float* wr = W2 + k * F_OUT;
        #pragma unroll
        for (int f = 0; f < F_OUT; ++f) acc[f] = fmaf(xv, wr[f], acc[f]);
    }
    int node = nb + lane;
    if (node < n) {
        float d = dinv[node];
        size_t R2 = ((size_t)n + 1) * 10;
        #pragma unroll
        for (int r = 0; r < 2; ++r)
            #pragma unroll
            for (int t = 0; t < 10; ++t)
                h2u[(size_t)r * R2 + (long)node * 10 + t] =
                    pack2(acc[r * 20 + 2 * t] * d, acc[r * 20 + 2 * t + 1] * d);
    }
}

// ---- conv2: 2 slices x 20 feats (40B rows), slice pinned to XCD quad,
//      10 lanes/node, NO unroll (4.0MB region: unroll thrashes, r7). ----
__global__ __launch_bounds__(256, 8) void k_conv2(
        const unsigned* __restrict__ h2u, const int* __restrict__ srcs,
        const int* __restrict__ off, const int* __restrict__ endp,
        const float* __restrict__ dinv, const float* __restrict__ b2,
        float* __restrict__ tmp, int n, int nb2) {
    int bid = blockIdx.x;
    int slice = (bid & 7) >> 2;
    int idx = ((bid >> 3) << 2) | (bid & 3);
    if (idx >= nb2) return;
    int lane = threadIdx.x & 63;
    bool lact = lane < 60;
    int g = lane / 10; if (g > 5) g = 5;
    int f = lane % 10;
    int gb = g * 10;
    const unsigned* base = h2u + (size_t)slice * (((size_t)n + 1) * 10);
    int node = idx * 24 + (threadIdx.x >> 6) * 6 + g;
    if (!lact) node = n;
    int nodec = (node < n) ? node : n;
    int j = (node < n) ? off[node] : 0;
    int e = (node < n) ? endp[node] : 0;
    float a0 = 0.f, a1 = 0.f;
    while (__any(j < e)) {
        int cnt = e - j;
        cnt = cnt < 0 ? 0 : (cnt > 10 ? 10 : cnt);
        int srcv = n;
        if (f < cnt && lact) srcv = srcs[j + f];
        #pragma unroll
        for (int k = 0; k < 10; ++k) {
            int s = __shfl(srcv, gb + k);
            unsigned u = base[(long)s * 10 + f];
            a0 += bflo(u);
            a1 += bfhi(u);
        }
        j += cnt;
    }
    unsigned us = base[(long)nodec * 10 + f];
    float d = (node < n) ? dinv[node] : 0.f;
    float2 bb = ((const float2*)b2)[slice * 10 + f];
    float v0 = d * (a0 + bflo(us)) + bb.x;
    float v1 = d * (a1 + bfhi(us)) + bb.y;
    if (node < n && lact) {
        float2 o;
        o.x = v0; o.y = v1;
        *(float2*)(tmp + (long)node * F_OUT + slice * 20 + 2 * f) = o;
    }
}

// ---- log_softmax over the 40 logits of each node; wave per node ----
__global__ __launch_bounds__(256) void k_lsm(const float* __restrict__ tmp,
                                             float* __restrict__ out, int n) {
    int t = blockIdx.x * 256 + threadIdx.x;
    int node = t >> 6, lane = t & 63;
    if (node >= n) return;
    float v = (lane < F_OUT) ? tmp[(long)node * F_OUT + lane] : -INFINITY;
    float m = v;
    #pragma unroll
    for (int o = 32; o > 0; o >>= 1) m = fmaxf(m, __shfl_xor(m, o));
    float ex = (lane < F_OUT) ? expf(v - m) : 0.f;
    float s = ex;
    #pragma unroll
    for (int o = 32; o > 0; o >>= 1) s += __shfl_xor(s, o);
    float lse = logf(s) + m;
    if (lane < F_OUT) out[(long)node * F_OUT + lane] = v - lse;
}

extern "C" void kernel_launch(void* const* d_in, const int* in_sizes, int n_in,
                              void* d_out, int out_size, void* d_ws, size_t ws_size,
                              hipStream_t stream) {
    const float* x     = (const float*)d_in[0];
    const int*   ei    = (const int*)d_in[1];
    const float* gamma = (const float*)d_in[2];
    const float* beta  = (const float*)d_in[3];
    const float* rmean = (const float*)d_in[4];
    const float* rvar  = (const float*)d_in[5];
    const float* W1    = (const float*)d_in[6];
    const float* b1    = (const float*)d_in[7];
    const float* W2    = (const float*)d_in[8];
    const float* b2    = (const float*)d_in[9];
    float* out = (float*)d_out;

    int n = in_sizes[0] / F_IN;
    int E = in_sizes[1] / 2;
    const int* row = ei;       // edge_index[0] = source
    const int* col = ei + E;   // edge_index[1] = target

    // binning geometry: 256 nodes/bucket, <=512 buckets, <=128 edge chunks
    // (r15: 128 chunks -> ~32-edge runs per (bucket,chunk) cell = full lines)
    int NB = (n + 255) >> 8;                          // 391 for n=100K
    int chunk = (E + 127) / 128;
    chunk = (chunk + 255) & ~255;
    if (chunk < 256) chunk = 256;
    int nblk = (E + chunk - 1) / chunk;               // <= 128

    int*   off    = (int*)d_ws;                       // n
    int*   endp   = off + n;                          // n
    float* dinv   = (float*)(endp + n);               // n
    int*   cursor = (int*)(dinv + n);                 // 4 ints
    int*   bb     = cursor + 4;                       // 512 bucket bases
    int*   btot   = bb + 512;                         // 512 bucket totals
    int*   bh     = btot + 512;                       // 512*512 cell table (oversize)
    int*   srcs   = bh + 512 * 512;                   // E ints
    unsigned* h1u = (unsigned*)(srcs + E);            // 4 regions x (n+1)*8 dwords
    unsigned* hu  = h1u + 4 * (((size_t)n + 1) * 8);  // 4 regions x n*8 (slice-major)
    unsigned* h2u = hu + (size_t)n * 32;              // 2 regions x (n+1)*10 dwords
    float* tmp    = (float*)h1u;      // n*40 fp32, aliases dead h1u+hu
    unsigned* bpk = hu;               // E dwords, aliases hu (dead until conv1)

    k_hist   <<<nblk, 256, 0, stream>>>(col, E, chunk, nblk, NB, bh, cursor);
    k_alloc  <<<NB,   256, 0, stream>>>(bh, bb, btot, cursor, nblk);
    k_scatter<<<nblk, 256, 0, stream>>>(row, col, E, chunk, nblk, NB, bh, bpk);
    k_fine   <<<NB,   256, 0, stream>>>(bpk, bb, btot, off, endp, dinv, srcs, n);

    k_gemm1<<<(n + 63) / 64, 256, 0, stream>>>(x, gamma, beta, rmean, rvar, W1,
                                               dinv, h1u, h2u, n);
    // conv1: 4 slices x nb1 node-blocks (32 nodes each); slice = (bid&7)>>1
    int nb1 = (n + 31) / 32;
    int nb1p = (nb1 + 1) & ~1;                        // even -> grid % 8 == 0
    k_conv1<<<4 * nb1p, 256, 0, stream>>>(h1u, srcs, off, endp, dinv, b1,
                                          hu, n, nb1);
    k_gemm2<<<(n + 63) / 64, 64, 0, stream>>>(hu, W2, dinv, h2u, n);
    // conv2: 2 slices x nb2 node-blocks (24 nodes each); slice = (bid&7)>>2
    int nb2 = (n + 23) / 24;
    int nb2p = (nb2 + 3) & ~3;                        // mult of 4 -> grid % 8 == 0
    k_conv2<<<2 * nb2p, 256, 0, stream>>>(h2u, srcs, off, endp, dinv, b2,
                                          tmp, n, nb2);
    k_lsm  <<<(n + 3) / 4, 256, 0, stream>>>(tmp, out, n);
}

// Round 16
// 290.506 us; speedup vs baseline: 1.0756x; 1.0756x over previous
//
#include <hip/hip_runtime.h>
#include <hip/hip_bf16.h>
#include <math.h>

#define F_IN 128
#define F_HID 64
#define F_OUT 40
#define BN_EPS 1e-5f

typedef __attribute__((ext_vector_type(8))) short short8;
typedef __attribute__((ext_vector_type(4))) float f32x4;

__device__ __forceinline__ float bflo(unsigned u) { return __uint_as_float(u << 16); }
__device__ __forceinline__ float bfhi(unsigned u) { return __uint_as_float(u & 0xffff0000u); }
__device__ __forceinline__ unsigned pack2(float a, float b) {
    __hip_bfloat162 p;
    p.x = __float2bfloat16(a);
    p.y = __float2bfloat16(b);
    return *(unsigned*)&p;
}

// ============ CSR build via 2-level LDS counting sort.
// r1: global atomics write through memory-side at 32B/op -> never on hot path.
// r4/r10: node reordering destroys locality -> natural node order everywhere.
// r6: edge-parallel LDS f32 atomics serialize on the LDS atomic pipe.
// r7/r8: per-XCD gather region must be < ~3.5MB; rows wide/aligned.
// r11: grid.sync costs ~60us each on 8 XCDs -> cooperative fusion dead.
// r12-r14: conv1 pinned at ~46us across 6 structural variants (mixed
//     VALU-issue + L2 random-service floor; not MLP, not VGPR, not requests).
// r15: nblk 128 starves the grid (scatter occupancy 3.9%, 46us) -> build
//     grid occupancy dominates partial-line write amp; nblk=512 is right.

// ---- pass 1: per-(bucket, block) coarse histogram; block 0 zeroes cursor ----
__global__ __launch_bounds__(256) void k_hist(const int* __restrict__ col, int E,
                                              int chunk, int nblk, int NB,
                                              int* __restrict__ bh,
                                              int* __restrict__ cursor) {
    __shared__ int hist[512];
    int t = threadIdx.x, blk = blockIdx.x;
    if (blk == 0 && t < 4) cursor[t] = 0;   // k_alloc runs in a later dispatch
    for (int i = t; i < NB; i += 256) hist[i] = 0;
    __syncthreads();
    int e0 = blk * chunk, e1 = min(E, e0 + chunk);
    for (int e = e0 + t; e < e1; e += 256)
        atomicAdd(&hist[col[e] >> 8], 1);
    __syncthreads();
    for (int i = t; i < NB; i += 256)
        bh[(size_t)i * nblk + blk] = hist[i];
}

// ---- pass 2: per-bucket scan of its nblk cells; 1 cursor atomic per bucket. ----
__global__ __launch_bounds__(256) void k_alloc(int* __restrict__ bh,
                                               int* __restrict__ bb,
                                               int* __restrict__ bt,
                                               int* __restrict__ cursor, int nblk) {
    int t = threadIdx.x, bu = blockIdx.x;
    int lane = t & 63, wv = t >> 6;
    size_t base_i = (size_t)bu * nblk;
    int i0 = 2 * t, i1 = 2 * t + 1;
    int a = (i0 < nblk) ? bh[base_i + i0] : 0;
    int b = (i1 < nblk) ? bh[base_i + i1] : 0;
    int p = a + b;
    int scan = p;
    #pragma unroll
    for (int o = 1; o < 64; o <<= 1) {
        int tt = __shfl_up(scan, o);
        if (lane >= o) scan += tt;
    }
    __shared__ int wsum[4];
    if (lane == 63) wsum[wv] = scan;
    __syncthreads();
    if (t == 0) {
        int s0 = wsum[0], s1 = wsum[1], s2 = wsum[2], s3 = wsum[3];
        int total = s0 + s1 + s2 + s3;
        int base = atomicAdd(cursor, total);
        bb[bu] = base;
        bt[bu] = total;
        wsum[0] = base; wsum[1] = base + s0;
        wsum[2] = base + s0 + s1; wsum[3] = base + s0 + s1 + s2;
    }
    __syncthreads();
    int excl = wsum[wv] + scan - p;   // absolute start of cell i0
    if (i0 < nblk) bh[base_i + i0] = excl;
    if (i1 < nblk) bh[base_i + i1] = excl + a;
}

// ---- pass 3: scatter edges into bucket-partitioned order via LDS cursors. ----
__global__ __launch_bounds__(256) void k_scatter(const int* __restrict__ row,
                                                 const int* __restrict__ col,
                                                 int E, int chunk, int nblk, int NB,
                                                 const int* __restrict__ bh,
                                                 unsigned* __restrict__ bpk) {
    __shared__ int cur[512];
    int t = threadIdx.x, blk = blockIdx.x;
    for (int i = t; i < NB; i += 256) cur[i] = bh[(size_t)i * nblk + blk];
    __syncthreads();
    int e0 = blk * chunk, e1 = min(E, e0 + chunk);
    for (int e = e0 + t; e < e1; e += 256) {
        int c = col[e];
        int pos = atomicAdd(&cur[c >> 8], 1);
        bpk[pos] = ((unsigned)row[e] << 8) | (unsigned)(c & 255);
    }
}

// ---- pass 4: per-bucket fine histogram + scan -> off/endp/dinv; place srcs. ----
__global__ __launch_bounds__(256) void k_fine(const unsigned* __restrict__ bpk,
                                              const int* __restrict__ bb,
                                              const int* __restrict__ bt,
                                              int* __restrict__ off,
                                              int* __restrict__ endp,
                                              float* __restrict__ dinv,
                                              int* __restrict__ srcs, int n) {
    __shared__ int fine[256];
    __shared__ int wsum[4];
    int t = threadIdx.x, bu = blockIdx.x;
    int lane = t & 63, wv = t >> 6;
    fine[t] = 0;
    __syncthreads();
    int base = bb[bu], tot = bt[bu];
    for (int i = t; i < tot; i += 256)
        atomicAdd(&fine[bpk[base + i] & 255], 1);
    __syncthreads();
    int d = fine[t];
    int scan = d;
    #pragma unroll
    for (int o = 1; o < 64; o <<= 1) {
        int tt = __shfl_up(scan, o);
        if (lane >= o) scan += tt;
    }
    if (lane == 63) wsum[wv] = scan;
    __syncthreads();
    if (t == 0) {
        int s0 = wsum[0], s1 = wsum[1], s2 = wsum[2];
        wsum[0] = 0;
        wsum[1] = s0;
        wsum[2] = s0 + s1;
        wsum[3] = s0 + s1 + s2;
    }
    __syncthreads();
    int o_node = base + wsum[wv] + scan - d;   // absolute segment start
    int node = bu * 256 + t;
    if (node < n) {
        off[node] = o_node;
        endp[node] = o_node + d;
        dinv[node] = rsqrtf((float)d + 1.0f);  // +1 self-loop
    }
    __syncthreads();
    fine[t] = o_node;                          // reuse as cursors
    __syncthreads();
    for (int i = t; i < tot; i += 256) {
        unsigned v = bpk[base + i];
        int pos = atomicAdd(&fine[v & 255], 1);
        srcs[pos] = (int)(v >> 8);
    }
}

// ---- h1' = dinv * (BN(x) @ W1) via MFMA bf16. Block 0 also zeroes the
//      h1u/h2u pad rows (row n) consumed by idle gather lanes. ----
__global__ __launch_bounds__(256) void k_gemm1(
        const float* __restrict__ x, const float* __restrict__ gamma,
        const float* __restrict__ beta, const float* __restrict__ mean,
        const float* __restrict__ var, const float* __restrict__ W1,
        const float* __restrict__ dinv, unsigned* __restrict__ h1u,
        unsigned* __restrict__ h2u, int n) {
    __shared__ unsigned short xt[64 * 136];     // 64 rows x 272B (pad 8 bf16)
    __shared__ float bs[F_IN], bt[F_IN];
    int t = threadIdx.x;
    if (blockIdx.x == 0) {
        size_t R1 = ((size_t)n + 1) * 8;
        size_t R2 = ((size_t)n + 1) * 10;
        if (t < 32) h1u[(size_t)(t >> 3) * R1 + (size_t)n * 8 + (t & 7)] = 0u;
        if (t >= 32 && t < 52) {
            int q = t - 32;
            h2u[(size_t)(q / 10) * R2 + (size_t)n * 10 + (q % 10)] = 0u;
        }
    }
    if (t < F_IN) {
        float s = rsqrtf(var[t] + BN_EPS) * gamma[t];
        bs[t] = s;
        bt[t] = beta[t] - mean[t] * s;
    }
    int lane = t & 63, wv = t >> 6;
    int quad = lane >> 4, c = lane & 15;
    short8 Bf[4][4];
    #pragma unroll
    for (int nt = 0; nt < 4; ++nt)
        #pragma unroll
        for (int ks = 0; ks < 4; ++ks) {
            short8 v;
            #pragma unroll
            for (int j = 0; j < 8; ++j) {
                int k = ks * 32 + quad * 8 + j;
                __hip_bfloat16 hb = __float2bfloat16(W1[k * F_HID + nt * 16 + c]);
                v[j] = *(short*)&hb;
            }
            Bf[nt][ks] = v;
        }
    __syncthreads();                            // bs/bt ready
    int nb = blockIdx.x * 64;
    #pragma unroll
    for (int it = 0; it < 8; ++it) {
        int i = t + 256 * it;                   // float4 slot: 2048 total
        int node = i >> 5, k4 = i & 31;
        int gn = nb + node;
        float4 v = make_float4(0.f, 0.f, 0.f, 0.f);
        if (gn < n) v = *(const float4*)(x + (size_t)gn * F_IN + k4 * 4);
        float4 sv = *(const float4*)(bs + k4 * 4);
        float4 tv = *(const float4*)(bt + k4 * 4);
        unsigned u0 = pack2(v.x * sv.x + tv.x, v.y * sv.y + tv.y);
        unsigned u1 = pack2(v.z * sv.z + tv.z, v.w * sv.w + tv.w);
        *(uint2*)(xt + node * 136 + k4 * 4) = make_uint2(u0, u1);
    }
    __syncthreads();
    const unsigned short* arow = xt + (wv * 16 + c) * 136;
    f32x4 acc[4] = {f32x4{0.f,0.f,0.f,0.f}, f32x4{0.f,0.f,0.f,0.f},
                    f32x4{0.f,0.f,0.f,0.f}, f32x4{0.f,0.f,0.f,0.f}};
    #pragma unroll
    for (int ks = 0; ks < 4; ++ks) {
        short8 af = *(const short8*)(arow + ks * 32 + quad * 8);  // ds_read_b128
        #pragma unroll
        for (int nt = 0; nt < 4; ++nt)
            acc[nt] = __builtin_amdgcn_mfma_f32_16x16x32_bf16(af, Bf[nt][ks],
                                                              acc[nt], 0, 0, 0);
    }
    size_t R1 = ((size_t)n + 1) * 8;
    #pragma unroll
    for (int r = 0; r < 4; ++r) {
        int node = nb + wv * 16 + quad * 4 + r;
        if (node < n) {
            float d = dinv[node];
            #pragma unroll
            for (int nt = 0; nt < 4; ++nt) {
                __hip_bfloat16 hb = __float2bfloat16(acc[nt][r] * d);
                unsigned short* dst =
                    (unsigned short*)(h1u + (size_t)nt * R1 + (size_t)node * 8) + c;
                *dst = *(unsigned short*)&hb;
            }
        }
    }
}

// ---- conv1: natural-order gather, slice pinned to XCD pair (3.2MB region,
//      L2-resident). 8 lanes/node, 4-batch unroll. ~46us floor (r12-r14). ----
__global__ __launch_bounds__(256, 8) void k_conv1(
        const unsigned* __restrict__ h1u, const int* __restrict__ srcs,
        const int* __restrict__ off, const int* __restrict__ endp,
        const float* __restrict__ dinv, const float* __restrict__ b1,
        unsigned* __restrict__ hus, int n, int nb1) {
    int bid = blockIdx.x;
    int slice = (bid & 7) >> 1;
    int idx = ((bid >> 3) << 1) | (bid & 1);
    if (idx >= nb1) return;
    int lane = threadIdx.x & 63;
    int g = lane >> 3, f = lane & 7, gb = g * 8;
    const unsigned* base = h1u + (size_t)slice * (((size_t)n + 1) * 8);
    int node = idx * 32 + (threadIdx.x >> 6) * 8 + g;
    int nodec = (node < n) ? node : n;
    int j = (node < n) ? off[node] : 0;
    int e = (node < n) ? endp[node] : 0;
    float a0 = 0.f, a1 = 0.f;
    while (__any(j < e)) {
        int sv0 = (j +      f < e) ? srcs[j + f]      : n;
        int sv1 = (j + 8  + f < e) ? srcs[j + 8 + f]  : n;
        int sv2 = (j + 16 + f < e) ? srcs[j + 16 + f] : n;
        int sv3 = (j + 24 + f < e) ? srcs[j + 24 + f] : n;
        #pragma unroll
        for (int k = 0; k < 8; ++k) {
            int s = __shfl(sv0, gb + k);
            unsigned u = base[(size_t)s * 8 + f];
            a0 += bflo(u); a1 += bfhi(u);
        }
        #pragma unroll
        for (int k = 0; k < 8; ++k) {
            int s = __shfl(sv1, gb + k);
            unsigned u = base[(size_t)s * 8 + f];
            a0 += bflo(u); a1 += bfhi(u);
        }
        #pragma unroll
        for (int k = 0; k < 8; ++k) {
            int s = __shfl(sv2, gb + k);
            unsigned u = base[(size_t)s * 8 + f];
            a0 += bflo(u); a1 += bfhi(u);
        }
        #pragma unroll
        for (int k = 0; k < 8; ++k) {
            int s = __shfl(sv3, gb + k);
            unsigned u = base[(size_t)s * 8 + f];
            a0 += bflo(u); a1 += bfhi(u);
        }
        j += 32;
    }
    unsigned us = base[(size_t)nodec * 8 + f];
    float d = (node < n) ? dinv[node] : 0.f;
    float2 bb = ((const float2*)b1)[slice * 8 + f];
    float h0 = fmaxf(d * (a0 + bflo(us)) + bb.x, 0.f);
    float h1 = fmaxf(d * (a1 + bfhi(us)) + bb.y, 0.f);
    if (node < n)
        hus[(size_t)slice * ((size_t)n * 8) + (size_t)node * 8 + f] = pack2(h0, h1);
}

// ---- h2' = dinv * (h @ W2); output 2 regions x (n+1)*10 dwords ----
__global__ __launch_bounds__(64) void k_gemm2(
        const unsigned* __restrict__ hus, const float* __restrict__ W2,
        const float* __restrict__ dinv, unsigned* __restrict__ h2u, int n) {
    __shared__ float xl[64 * 66];
    int lane = threadIdx.x;
    int nb = blockIdx.x * 64;
    int tn = lane >> 5;
    int q = lane & 31;
    size_t hN = (size_t)n * 8;
    for (int it = 0; it < 32; ++it) {
        int r = it * 2 + tn;
        int node = nb + r;
        unsigned u = 0;
        if (node < n) u = hus[(size_t)(q >> 3) * hN + (long)node * 8 + (q & 7)];
        xl[r * 66 + 2 * q]     = bflo(u);
        xl[r * 66 + 2 * q + 1] = bfhi(u);
    }
    __syncthreads();
    float acc[F_OUT];
    #pragma unroll
    for (int f = 0; f < F_OUT; ++f) acc[f] = 0.f;
    for (int k = 0; k < F_HID; ++k) {
        float xv = xl[lane * 66 + k];
        const float* wr = W2 + k * F_OUT;
        #pragma unroll
        for (int f = 0; f < F_OUT; ++f) acc[f] = fmaf(xv, wr[f], acc[f]);
    }
    int node = nb + lane;
    if (node < n) {
        float d = dinv[node];
        size_t R2 = ((size_t)n + 1) * 10;
        #pragma unroll
        for (int r = 0; r < 2; ++r)
            #pragma unroll
            for (int t = 0; t < 10; ++t)
                h2u[(size_t)r * R2 + (long)node * 10 + t] =
                    pack2(acc[r * 20 + 2 * t] * d, acc[r * 20 + 2 * t + 1] * d);
    }
}

// ---- conv2: 2 slices x 20 feats (40B rows), slice pinned to XCD quad,
//      10 lanes/node, NO unroll (4.0MB region: unroll thrashes, r7). ----
__global__ __launch_bounds__(256, 8) void k_conv2(
        const unsigned* __restrict__ h2u, const int* __restrict__ srcs,
        const int* __restrict__ off, const int* __restrict__ endp,
        const float* __restrict__ dinv, const float* __restrict__ b2,
        float* __restrict__ tmp, int n, int nb2) {
    int bid = blockIdx.x;
    int slice = (bid & 7) >> 2;
    int idx = ((bid >> 3) << 2) | (bid & 3);
    if (idx >= nb2) return;
    int lane = threadIdx.x & 63;
    bool lact = lane < 60;
    int g = lane / 10; if (g > 5) g = 5;
    int f = lane % 10;
    int gb = g * 10;
    const unsigned* base = h2u + (size_t)slice * (((size_t)n + 1) * 10);
    int node = idx * 24 + (threadIdx.x >> 6) * 6 + g;
    if (!lact) node = n;
    int nodec = (node < n) ? node : n;
    int j = (node < n) ? off[node] : 0;
    int e = (node < n) ? endp[node] : 0;
    float a0 = 0.f, a1 = 0.f;
    while (__any(j < e)) {
        int cnt = e - j;
        cnt = cnt < 0 ? 0 : (cnt > 10 ? 10 : cnt);
        int srcv = n;
        if (f < cnt && lact) srcv = srcs[j + f];
        #pragma unroll
        for (int k = 0; k < 10; ++k) {
            int s = __shfl(srcv, gb + k);
            unsigned u = base[(long)s * 10 + f];
            a0 += bflo(u);
            a1 += bfhi(u);
        }
        j += cnt;
    }
    unsigned us = base[(long)nodec * 10 + f];
    float d = (node < n) ? dinv[node] : 0.f;
    float2 bb = ((const float2*)b2)[slice * 10 + f];
    float v0 = d * (a0 + bflo(us)) + bb.x;
    float v1 = d * (a1 + bfhi(us)) + bb.y;
    if (node < n && lact) {
        float2 o;
        o.x = v0; o.y = v1;
        *(float2*)(tmp + (long)node * F_OUT + slice * 20 + 2 * f) = o;
    }
}

// ---- log_softmax over the 40 logits of each node; wave per node ----
__global__ __launch_bounds__(256) void k_lsm(const float* __restrict__ tmp,
                                             float* __restrict__ out, int n) {
    int t = blockIdx.x * 256 + threadIdx.x;
    int node = t >> 6, lane = t & 63;
    if (node >= n) return;
    float v = (lane < F_OUT) ? tmp[(long)node * F_OUT + lane] : -INFINITY;
    float m = v;
    #pragma unroll
    for (int o = 32; o > 0; o >>= 1) m = fmaxf(m, __shfl_xor(m, o));
    float ex = (lane < F_OUT) ? expf(v - m) : 0.f;
    float s = ex;
    #pragma unroll
    for (int o = 32; o > 0; o >>= 1) s += __shfl_xor(s, o);
    float lse = logf(s) + m;
    if (lane < F_OUT) out[(long)node * F_OUT + lane] = v - lse;
}

extern "C" void kernel_launch(void* const* d_in, const int* in_sizes, int n_in,
                              void* d_out, int out_size, void* d_ws, size_t ws_size,
                              hipStream_t stream) {
    const float* x     = (const float*)d_in[0];
    const int*   ei    = (const int*)d_in[1];
    const float* gamma = (const float*)d_in[2];
    const float* beta  = (const float*)d_in[3];
    const float* rmean = (const float*)d_in[4];
    const float* rvar  = (const float*)d_in[5];
    const float* W1    = (const float*)d_in[6];
    const float* b1    = (const float*)d_in[7];
    const float* W2    = (const float*)d_in[8];
    const float* b2    = (const float*)d_in[9];
    float* out = (float*)d_out;

    int n = in_sizes[0] / F_IN;
    int E = in_sizes[1] / 2;
    const int* row = ei;       // edge_index[0] = source
    const int* col = ei + E;   // edge_index[1] = target

    // binning geometry: 256 nodes/bucket, <=512 buckets, <=512 edge chunks
    // (r15 lesson: fewer chunks starves the grid; 512 is right)
    int NB = (n + 255) >> 8;                          // 391 for n=100K
    int chunk = (E + 511) / 512;
    chunk = (chunk + 255) & ~255;
    if (chunk < 256) chunk = 256;
    int nblk = (E + chunk - 1) / chunk;               // <= 512

    int*   off    = (int*)d_ws;                       // n
    int*   endp   = off + n;                          // n
    float* dinv   = (float*)(endp + n);               // n
    int*   cursor = (int*)(dinv + n);                 // 4 ints
    int*   bb     = cursor + 4;                       // 512 bucket bases
    int*   btot   = bb + 512;                         // 512 bucket totals
    int*   bh     = btot + 512;                       // 512*512 cell table
    int*   srcs   = bh + 512 * 512;                   // E ints
    unsigned* h1u = (unsigned*)(srcs + E);            // 4 regions x (n+1)*8 dwords
    unsigned* hu  = h1u + 4 * (((size_t)n + 1) * 8);  // 4 regions x n*8 (slice-major)
    unsigned* h2u = hu + (size_t)n * 32;              // 2 regions x (n+1)*10 dwords
    float* tmp    = (float*)h1u;      // n*40 fp32, aliases dead h1u+hu
    unsigned* bpk = hu;               // E dwords, aliases hu (dead until conv1)

    k_hist   <<<nblk, 256, 0, stream>>>(col, E, chunk, nblk, NB, bh, cursor);
    k_alloc  <<<NB,   256, 0, stream>>>(bh, bb, btot, cursor, nblk);
    k_scatter<<<nblk, 256, 0, stream>>>(row, col, E, chunk, nblk, NB, bh, bpk);
    k_fine   <<<NB,   256, 0, stream>>>(bpk, bb, btot, off, endp, dinv, srcs, n);

    k_gemm1<<<(n + 63) / 64, 256, 0, stream>>>(x, gamma, beta, rmean, rvar, W1,
                                               dinv, h1u, h2u, n);
    // conv1: 4 slices x nb1 node-blocks (32 nodes each); slice = (bid&7)>>1
    int nb1 = (n + 31) / 32;
    int nb1p = (nb1 + 1) & ~1;                        // even -> grid % 8 == 0
    k_conv1<<<4 * nb1p, 256, 0, stream>>>(h1u, srcs, off, endp, dinv, b1,
                                          hu, n, nb1);
    k_gemm2<<<(n + 63) / 64, 64, 0, stream>>>(hu, W2, dinv, h2u, n);
    // conv2: 2 slices x nb2 node-blocks (24 nodes each); slice = (bid&7)>>2
    int nb2 = (n + 23) / 24;
    int nb2p = (nb2 + 3) & ~3;                        // mult of 4 -> grid % 8 == 0
    k_conv2<<<2 * nb2p, 256, 0, stream>>>(h2u, srcs, off, endp, dinv, b2,
                                          tmp, n, nb2);
    k_lsm  <<<(n + 3) / 4, 256, 0, stream>>>(tmp, out, n);
}